// Round 6
// baseline (2279.795 us; speedup 1.0000x reference)
//
#include <hip/hip_runtime.h>
#include <stdint.h>

// Problem constants (ComplexChebTemporalConv)
#define Bn 4
#define Nn 2048
#define Tn 64
#define CIn 32
#define COn 32
#define Kn 6
#define TAUn 3
#define Jn 8192  // B*T*CI

typedef _Float16 f16;
typedef _Float16 f16x2 __attribute__((ext_vector_type(2)));
typedef _Float16 f16x4 __attribute__((ext_vector_type(4)));
typedef _Float16 f16x8 __attribute__((ext_vector_type(8)));
typedef float f32x4 __attribute__((ext_vector_type(4)));

#if defined(__has_builtin)
#if __has_builtin(__builtin_amdgcn_fdot2)
#define HAVE_FDOT2 1
#endif
#endif

__device__ __forceinline__ float fdot2(f16x2 a, f16x2 b, float c) {
#ifdef HAVE_FDOT2
  return __builtin_amdgcn_fdot2(a, b, c, false);
#else
  return c + (float)a[0] * (float)b[0] + (float)a[1] * (float)b[1];
#endif
}

__device__ __forceinline__ void gld_lds16(const void* g, void* l) {
  auto gp = (const __attribute__((address_space(1))) uint32_t*)(uintptr_t)g;
  auto lp = (__attribute__((address_space(3))) uint32_t*)(uint32_t)(uintptr_t)l;
  __builtin_amdgcn_global_load_lds(gp, lp, 16, 0, 0);
}

// ---------------------------------------------------------------------------
// pack_gso: fp32 gso planes -> f16 planes (row-major [n][m])
// ---------------------------------------------------------------------------
__global__ __launch_bounds__(256) void pack_gso(const float* __restrict__ gr,
                                                const float* __restrict__ gi,
                                                f16* __restrict__ Gr,
                                                f16* __restrict__ Gi) {
  int u = blockIdx.x * 256 + threadIdx.x;
  float4 vr = ((const float4*)gr)[u];
  float4 vi = ((const float4*)gi)[u];
  f16x4 hr, hi;
  hr[0] = (f16)vr.x; hr[1] = (f16)vr.y; hr[2] = (f16)vr.z; hr[3] = (f16)vr.w;
  hi[0] = (f16)vi.x; hi[1] = (f16)vi.y; hi[2] = (f16)vi.z; hi[3] = (f16)vi.w;
  ((f16x4*)Gr)[u] = hr;
  ((f16x4*)Gi)[u] = hi;
}

// ---------------------------------------------------------------------------
// pack_x: x [b][n][q] fp32 -> combined P0[j=b*2048+q][4096]: re at col n, im at 2048+n
// ---------------------------------------------------------------------------
__global__ __launch_bounds__(256) void pack_x(const float* __restrict__ xr,
                                              const float* __restrict__ xi,
                                              f16* __restrict__ P0) {
  __shared__ float tile[64][65];
  const int t = threadIdx.x;
  const int q0 = blockIdx.x * 64;
  const int n0 = blockIdx.y * 64;
  const int b = blockIdx.z;
  const int rr = t >> 4;
  const int cc = (t & 15) * 4;
  #pragma unroll
  for (int plane = 0; plane < 2; ++plane) {
    const float* src = plane ? xi : xr;
    if (plane) __syncthreads();
    #pragma unroll
    for (int it = 0; it < 4; ++it) {
      int n = it * 16 + rr;
      float4 v = *(const float4*)(src + ((size_t)b * Nn + n0 + n) * 2048 + q0 + cc);
      tile[n][cc + 0] = v.x; tile[n][cc + 1] = v.y;
      tile[n][cc + 2] = v.z; tile[n][cc + 3] = v.w;
    }
    __syncthreads();
    #pragma unroll
    for (int it = 0; it < 4; ++it) {
      int q = it * 16 + rr;
      f16x4 hv;
      hv[0] = (f16)tile[cc + 0][q];
      hv[1] = (f16)tile[cc + 1][q];
      hv[2] = (f16)tile[cc + 2][q];
      hv[3] = (f16)tile[cc + 3][q];
      *(f16x4*)(P0 + ((size_t)b * 2048 + q0 + q) * 4096 + plane * 2048 + n0 + cc) = hv;
    }
  }
}

// ---------------------------------------------------------------------------
// pack_w: wpk[idx].x = (wr, -wi), wpk[idx].y = (wi, wr); idx = [k][tau][ci][co]
// ---------------------------------------------------------------------------
__global__ __launch_bounds__(256) void pack_w(const float* __restrict__ wr,
                                              const float* __restrict__ wi,
                                              uint2* __restrict__ wpk) {
  int idx = blockIdx.x * 256 + threadIdx.x;
  if (idx >= Kn * TAUn * CIn * COn) return;
  float r = wr[idx], i = wi[idx];
  uint16_t hr = __builtin_bit_cast(uint16_t, (f16)r);
  uint16_t hi = __builtin_bit_cast(uint16_t, (f16)i);
  uint16_t hni = __builtin_bit_cast(uint16_t, (f16)(-i));
  uint2 o;
  o.x = (uint32_t)hr | ((uint32_t)hni << 16);
  o.y = (uint32_t)hi | ((uint32_t)hr << 16);
  wpk[idx] = o;
}

// ---------------------------------------------------------------------------
// cheb_gemm: embedded-real complex GEMM.
//   C[n'][j] = sum_{k'} G2[n'][k'] * P[j][k'],  n',k' in [0,4096), j in [0,8192)
//   G2 = [[Gr,-Gi],[Gi,Gr]] (negation applied in-register on A fragments).
// MODE 0: Q = C ; MODE 1: Q = 2C - Q (in place).
// 512 thr = 8 waves as 2(M) x 4(N) grid; tile 256(n') x 256(j), BK=64,
// wave-tile 128 x 64 -> 24 ds_read_b128 per wave per K-tile (vs 36 at 1x8).
// LDS 128KiB, 8 x 16KB half-slots SPLIT ALONG K: slot = all 256 rows x 32 k.
// A slots {cur*2, cur*2+1}, B slots {4+cur*2, 5+cur*2} (double buffer).
// Phases 0-1 compute ks=0 (Ah0+Bh0/1, covered by boundary vmcnt(2));
// phases 2-3 compute ks=1 (Ah1 covered by mid vmcnt(4)).
// Stage order/slots/gates bit-identical to r2-proven schedule.
// XCD swizzle (FETCH-proven): bj = xcd*4 + (l>>4), bn = l&15.
// ---------------------------------------------------------------------------
template <int MODE>
__global__ __launch_bounds__(512, 2) void cheb_gemm(
    const f16* __restrict__ Gr, const f16* __restrict__ Gi,
    const f16* __restrict__ P, f16* __restrict__ Q) {
  extern __shared__ __align__(16) char lds[];
  f16* L = (f16*)lds;

  const int tid = threadIdx.x;
  const int lane = tid & 63;
  const int w = tid >> 6;
  const int wm = w >> 2;              // 0..1 : 128-row n'-strip
  const int wn = w & 3;               // 0..3 : 64-row j-strip
  const int sub = lane >> 4, rr = lane & 15;

  const int bid = blockIdx.x;
  const int xcd = bid & 7;
  const int l = bid >> 3;             // 0..63 in-XCD
  const int bj = xcd * 4 + (l >> 4);
  const int bn = l & 15;
  const int n0 = bn * 256, j0 = bj * 256;
  const bool top = n0 < 2048;
  const int gmbase = n0 & 2047;

  // stage one k-half chunk: 256 rows x 32 k = 16KB = 2 ops/thread.
  // u = c*256 + row, c = 16B k-chunk index (chunk-major, matches frag reads).
  auto stageA = [&](const f16* plane, int kcol, int h, int slot) {
    #pragma unroll
    for (int p = 0; p < 2; ++p) {
      int u = p * 512 + tid;
      int row = u & 255, c = u >> 8;
      const f16* src = plane + (size_t)(gmbase + row) * 2048 + kcol + h * 32 + c * 8;
      gld_lds16(src, L + slot * 8192 + (u - lane) * 8);
    }
  };
  auto stageB = [&](int kt, int h, int slot) {
    #pragma unroll
    for (int p = 0; p < 2; ++p) {
      int u = p * 512 + tid;
      int row = u & 255, c = u >> 8;
      const f16* src = P + (size_t)(j0 + row) * 4096 + kt * 64 + h * 32 + c * 8;
      gld_lds16(src, L + slot * 8192 + (u - lane) * 8);
    }
  };
  auto Aplane = [&](int kt) -> const f16* {
    bool kr = (kt & 32) != 0;  // k' >= 2048
    return top ? (kr ? Gi : Gr) : (kr ? Gr : Gi);
  };

  f32x4 acc[8][4] = {};
  f16x8 bfr[4];

  // prologue: stage tile 0 (B halves, then A halves — order fixes vmcnt counts)
  stageB(0, 0, 4); stageB(0, 1, 5);
  stageA(Aplane(0), 0, 0, 0); stageA(Aplane(0), 0, 1, 1);

  for (int kt = 0; kt < 64; ++kt) {
    const int cur = kt & 1;
    const int nxt = cur ^ 1;
    const int ktn = (kt + 1) & 63;  // wrap -> dummy re-stage of tile 0 keeps counts uniform
    const f16* apn = Aplane(ktn);
    const int kcoln = (ktn * 64) & 2047;
    const bool negA = top && (kt & 32);
    const int Abase = (cur * 2) * 8192;
    const int Bbase = (4 + cur * 2) * 8192;

    // boundary gate: Bh0,Bh1,Ah0 of tile kt visible; Ah1 may still be in flight
    asm volatile("s_waitcnt vmcnt(2)" ::: "memory");
    __builtin_amdgcn_s_barrier();

    #pragma unroll
    for (int p = 0; p < 4; ++p) {
      if (p == 2) {
        // mid gate: Ah1(kt) visible; tile kt+1's B stays in flight
        asm volatile("s_waitcnt vmcnt(4)" ::: "memory");
        __builtin_amdgcn_s_barrier();
      }
      const int ksh = p >> 1;   // k-half of this phase pair
      const int fh = p & 1;     // fragment-row half: fr = fh*4 .. fh*4+3

      if (fh == 0) {
        // (re)load B fragments for this k-half: rows wn*64 + fc*16 + rr
        #pragma unroll
        for (int fc = 0; fc < 4; ++fc)
          bfr[fc] = *(const f16x8*)(L + Bbase + ksh * 8192 +
                                    (sub * 256 + wn * 64 + fc * 16 + rr) * 8);
      }
      f16x8 afr[4];
      #pragma unroll
      for (int f = 0; f < 4; ++f)
        afr[f] = *(const f16x8*)(L + Abase + ksh * 8192 +
                                 (sub * 256 + wm * 128 + (fh * 4 + f) * 16 + rr) * 8);

      // fine-interleaved prefetch of tile kt+1 (same call sites/slots as r2)
      if (p == 0) stageB(ktn, 0, 4 + nxt * 2);
      if (p == 1) stageB(ktn, 1, 5 + nxt * 2);
      if (p == 2) stageA(apn, kcoln, 0, nxt * 2);
      if (p == 3) stageA(apn, kcoln, 1, nxt * 2 + 1);

      if (negA) {
        #pragma unroll
        for (int f = 0; f < 4; ++f) afr[f] = -afr[f];
      }
      __builtin_amdgcn_s_setprio(1);
      #pragma unroll
      for (int f = 0; f < 4; ++f)
        #pragma unroll
        for (int fc = 0; fc < 4; ++fc)
          acc[fh * 4 + f][fc] = __builtin_amdgcn_mfma_f32_16x16x32_f16(
              afr[f], bfr[fc], acc[fh * 4 + f][fc], 0, 0, 0);
      __builtin_amdgcn_s_setprio(0);
    }
  }

  asm volatile("s_waitcnt vmcnt(0)" ::: "memory");

  // Epilogue: transposed write Q[j][n']; C/D map col=lane&15, row=(lane>>4)*4+r
  #pragma unroll
  for (int fc = 0; fc < 4; ++fc) {
    size_t j = (size_t)j0 + wn * 64 + fc * 16 + (lane & 15);
    #pragma unroll
    for (int fr = 0; fr < 8; ++fr) {
      int nn = n0 + wm * 128 + fr * 16 + ((lane >> 4) << 2);
      size_t off = j * 4096 + nn;
      f16x4 v;
      if (MODE == 1) {
        f16x4 o = *(const f16x4*)(Q + off);
        #pragma unroll
        for (int r = 0; r < 4; ++r)
          v[r] = (f16)(2.0f * acc[fr][fc][r] - (float)o[r]);
      } else {
        #pragma unroll
        for (int r = 0; r < 4; ++r)
          v[r] = (f16)acc[fr][fc][r];
      }
      *(f16x4*)(Q + off) = v;
    }
  }
}

// ---------------------------------------------------------------------------
// contract_k: out[b][n][t][o] (+)= sum_{tau,i} Re/Im( P_k[b,n,t-tau,i]*w[k,tau,i,o] )
// P combined plane: re at [j][n], im at [j][2048+n], row stride 4096.
// ---------------------------------------------------------------------------
template <bool CPLX>
__global__ __launch_bounds__(256, 4) void contract_k(
    const f16* __restrict__ Pc, const uint2* __restrict__ wpk,
    const float* __restrict__ biasr, const float* __restrict__ biasi,
    float* __restrict__ out, int k) {
  __shared__ __align__(16) uint32_t Plds[96 * 64];
  __shared__ __align__(16) uint32_t WA[96 * 32];
  __shared__ __align__(16) uint32_t WB[CPLX ? 96 * 32 : 32];

  const int t = threadIdx.x;
  const int n0 = blockIdx.x * 64;
  const int tt = blockIdx.y;
  const int b = blockIdx.z;

  #pragma unroll
  for (int it = 0; it < 3; ++it) {
    int task = it * 256 + t;
    int row = task >> 3, oc = task & 7;
    int tp = (tt - 2) * 32 + row;
    uint4 ur = {0, 0, 0, 0}, ui = {0, 0, 0, 0};
    if (tp >= 0) {
      size_t goff = ((size_t)b * 2048 + tp) * 4096 + n0 + oc * 8;
      ur = *(const uint4*)(Pc + goff);
      ui = *(const uint4*)(Pc + goff + 2048);
    }
    uint32_t* dst = &Plds[row * 64 + oc * 8];
    dst[0] = (ur.x & 0xffffu) | (ui.x << 16);
    dst[1] = (ur.x >> 16) | (ui.x & 0xffff0000u);
    dst[2] = (ur.y & 0xffffu) | (ui.y << 16);
    dst[3] = (ur.y >> 16) | (ui.y & 0xffff0000u);
    dst[4] = (ur.z & 0xffffu) | (ui.z << 16);
    dst[5] = (ur.z >> 16) | (ui.z & 0xffff0000u);
    dst[6] = (ur.w & 0xffffu) | (ui.w << 16);
    dst[7] = (ur.w >> 16) | (ui.w & 0xffff0000u);
  }
  #pragma unroll
  for (int it = 0; it < 12; ++it) {
    int idx = it * 256 + t;
    int q = idx >> 5, o = idx & 31;
    int tau = 2 - (q >> 5), ci = q & 31;
    uint2 wv = wpk[((k * TAUn + tau) * CIn + ci) * COn + o];
    WA[idx] = wv.x;
    if (CPLX) WB[idx] = wv.y;
  }
  __syncthreads();

  const int no = t & 7, ng = t >> 3;
  float aR[8] = {0, 0, 0, 0, 0, 0, 0, 0};
  float aI[8] = {0, 0, 0, 0, 0, 0, 0, 0};
  for (int q = 0; q < 96; ++q) {
    uint2 pp = *(const uint2*)&Plds[q * 64 + ng * 2];
    f16x2 h0 = __builtin_bit_cast(f16x2, pp.x);
    f16x2 h1 = __builtin_bit_cast(f16x2, pp.y);
    uint4 wa = *(const uint4*)&WA[q * 32 + no * 4];
    const uint32_t* wap = &wa.x;
    #pragma unroll
    for (int c = 0; c < 4; ++c) {
      f16x2 wv = __builtin_bit_cast(f16x2, wap[c]);
      aR[c] = fdot2(h0, wv, aR[c]);
      aR[4 + c] = fdot2(h1, wv, aR[4 + c]);
    }
    if (CPLX) {
      uint4 wb = *(const uint4*)&WB[q * 32 + no * 4];
      const uint32_t* wbp = &wb.x;
      #pragma unroll
      for (int c = 0; c < 4; ++c) {
        f16x2 wv = __builtin_bit_cast(f16x2, wbp[c]);
        aI[c] = fdot2(h0, wv, aI[c]);
        aI[4 + c] = fdot2(h1, wv, aI[4 + c]);
      }
    }
  }

  #pragma unroll
  for (int a = 0; a < 2; ++a) {
    size_t n = (size_t)n0 + ng * 2 + a;
    size_t ob = (((size_t)b * Nn + n) * Tn + tt) * COn + no * 4;
    if (!CPLX) {
      float4 v;
      v.x = aR[a * 4 + 0]; v.y = aR[a * 4 + 1];
      v.z = aR[a * 4 + 2]; v.w = aR[a * 4 + 3];
      float4 cur;
      if (k == 0) cur = *(const float4*)(biasr + no * 4);
      else cur = *(const float4*)(out + ob);
      v.x += cur.x; v.y += cur.y; v.z += cur.z; v.w += cur.w;
      *(float4*)(out + ob) = v;
    } else {
      float* po = out + ob * 2;
      float4 lo, hi;
      lo.x = aR[a * 4 + 0]; lo.y = aI[a * 4 + 0];
      lo.z = aR[a * 4 + 1]; lo.w = aI[a * 4 + 1];
      hi.x = aR[a * 4 + 2]; hi.y = aI[a * 4 + 2];
      hi.z = aR[a * 4 + 3]; hi.w = aI[a * 4 + 3];
      float4 c0, c1;
      if (k == 0) {
        const float* pr = biasr + no * 4;
        const float* pi = biasi + no * 4;
        c0 = make_float4(pr[0], pi[0], pr[1], pi[1]);
        c1 = make_float4(pr[2], pi[2], pr[3], pi[3]);
      } else {
        c0 = *(const float4*)(po);
        c1 = *(const float4*)(po + 4);
      }
      lo.x += c0.x; lo.y += c0.y; lo.z += c0.z; lo.w += c0.w;
      hi.x += c1.x; hi.y += c1.y; hi.z += c1.z; hi.w += c1.w;
      *(float4*)(po) = lo;
      *(float4*)(po + 4) = hi;
    }
  }
}

// ---------------------------------------------------------------------------
extern "C" void kernel_launch(void* const* d_in, const int* in_sizes, int n_in,
                              void* d_out, int out_size, void* d_ws, size_t ws_size,
                              hipStream_t stream) {
  (void)in_sizes; (void)n_in;
  const float* xr = (const float*)d_in[0];
  const float* xi = (const float*)d_in[1];
  const float* gr = (const float*)d_in[2];
  const float* gi = (const float*)d_in[3];
  const float* wr = (const float*)d_in[4];
  const float* wi = (const float*)d_in[5];
  const float* biasr = (const float*)d_in[6];
  const float* biasi = (const float*)d_in[7];
  float* out = (float*)d_out;

  const size_t PPLANE = (size_t)Jn * 4096 * sizeof(f16);  // 67,108,864 (combined)
  const size_t GPLANE = (size_t)Nn * Nn * sizeof(f16);    // 8,388,608
  const size_t WPK = (size_t)Kn * TAUn * CIn * COn * 8;   // 147,456
  if (ws_size < 2 * PPLANE + 2 * GPLANE + WPK) return;

  char* ws = (char*)d_ws;
  f16* P0 = (f16*)(ws);
  f16* P1 = (f16*)(ws + PPLANE);
  f16* Gr = (f16*)(ws + 2 * PPLANE);
  f16* Gi = (f16*)(ws + 2 * PPLANE + GPLANE);
  uint2* wpk = (uint2*)(ws + 2 * PPLANE + 2 * GPLANE);

  const bool cplx = (out_size == 2 * Bn * Nn * Tn * COn);

  pack_gso<<<dim3(4096), dim3(256), 0, stream>>>(gr, gi, Gr, Gi);
  pack_x<<<dim3(32, 32, 4), dim3(256), 0, stream>>>(xr, xi, P0);
  pack_w<<<dim3(72), dim3(256), 0, stream>>>(wr, wi, wpk);

  #define CONTRACT(KK, Pp)                                                         \
    do {                                                                           \
      if (cplx)                                                                    \
        contract_k<true><<<dim3(32, 64, 4), dim3(256), 0, stream>>>(               \
            Pp, wpk, biasr, biasi, out, KK);                                       \
      else                                                                         \
        contract_k<false><<<dim3(32, 64, 4), dim3(256), 0, stream>>>(              \
            Pp, wpk, biasr, biasi, out, KK);                                       \
    } while (0)

  CONTRACT(0, P0);
  cheb_gemm<0><<<dim3(512), dim3(512), 131072, stream>>>(Gr, Gi, P0, P1);
  CONTRACT(1, P1);
  cheb_gemm<1><<<dim3(512), dim3(512), 131072, stream>>>(Gr, Gi, P1, P0);
  CONTRACT(2, P0);
  cheb_gemm<1><<<dim3(512), dim3(512), 131072, stream>>>(Gr, Gi, P0, P1);
  CONTRACT(3, P1);
  cheb_gemm<1><<<dim3(512), dim3(512), 131072, stream>>>(Gr, Gi, P1, P0);
  CONTRACT(4, P0);
  cheb_gemm<1><<<dim3(512), dim3(512), 131072, stream>>>(Gr, Gi, P0, P1);
  CONTRACT(5, P1);
  #undef CONTRACT
}

// Round 7
// 2040.818 us; speedup vs baseline: 1.1171x; 1.1171x over previous
//
#include <hip/hip_runtime.h>
#include <stdint.h>

// Problem constants (ComplexChebTemporalConv)
#define Bn 4
#define Nn 2048
#define Tn 64
#define CIn 32
#define COn 32
#define Kn 6
#define TAUn 3
#define Jn 8192  // B*T*CI

typedef _Float16 f16;
typedef _Float16 f16x2 __attribute__((ext_vector_type(2)));
typedef _Float16 f16x4 __attribute__((ext_vector_type(4)));
typedef _Float16 f16x8 __attribute__((ext_vector_type(8)));
typedef float f32x4 __attribute__((ext_vector_type(4)));

#if defined(__has_builtin)
#if __has_builtin(__builtin_amdgcn_fdot2)
#define HAVE_FDOT2 1
#endif
#endif

__device__ __forceinline__ float fdot2(f16x2 a, f16x2 b, float c) {
#ifdef HAVE_FDOT2
  return __builtin_amdgcn_fdot2(a, b, c, false);
#else
  return c + (float)a[0] * (float)b[0] + (float)a[1] * (float)b[1];
#endif
}

__device__ __forceinline__ void gld_lds16(const void* g, void* l) {
  auto gp = (const __attribute__((address_space(1))) uint32_t*)(uintptr_t)g;
  auto lp = (__attribute__((address_space(3))) uint32_t*)(uint32_t)(uintptr_t)l;
  __builtin_amdgcn_global_load_lds(gp, lp, 16, 0, 0);
}

// ---------------------------------------------------------------------------
// pack_gso: fp32 gso planes -> f16 planes (row-major [n][m])
// ---------------------------------------------------------------------------
__global__ __launch_bounds__(256) void pack_gso(const float* __restrict__ gr,
                                                const float* __restrict__ gi,
                                                f16* __restrict__ Gr,
                                                f16* __restrict__ Gi) {
  int u = blockIdx.x * 256 + threadIdx.x;
  float4 vr = ((const float4*)gr)[u];
  float4 vi = ((const float4*)gi)[u];
  f16x4 hr, hi;
  hr[0] = (f16)vr.x; hr[1] = (f16)vr.y; hr[2] = (f16)vr.z; hr[3] = (f16)vr.w;
  hi[0] = (f16)vi.x; hi[1] = (f16)vi.y; hi[2] = (f16)vi.z; hi[3] = (f16)vi.w;
  ((f16x4*)Gr)[u] = hr;
  ((f16x4*)Gi)[u] = hi;
}

// ---------------------------------------------------------------------------
// pack_x: x [b][n][q] fp32 -> combined P0[j=b*2048+q][4096]: re at col n, im at 2048+n
// ---------------------------------------------------------------------------
__global__ __launch_bounds__(256) void pack_x(const float* __restrict__ xr,
                                              const float* __restrict__ xi,
                                              f16* __restrict__ P0) {
  __shared__ float tile[64][65];
  const int t = threadIdx.x;
  const int q0 = blockIdx.x * 64;
  const int n0 = blockIdx.y * 64;
  const int b = blockIdx.z;
  const int rr = t >> 4;
  const int cc = (t & 15) * 4;
  #pragma unroll
  for (int plane = 0; plane < 2; ++plane) {
    const float* src = plane ? xi : xr;
    if (plane) __syncthreads();
    #pragma unroll
    for (int it = 0; it < 4; ++it) {
      int n = it * 16 + rr;
      float4 v = *(const float4*)(src + ((size_t)b * Nn + n0 + n) * 2048 + q0 + cc);
      tile[n][cc + 0] = v.x; tile[n][cc + 1] = v.y;
      tile[n][cc + 2] = v.z; tile[n][cc + 3] = v.w;
    }
    __syncthreads();
    #pragma unroll
    for (int it = 0; it < 4; ++it) {
      int q = it * 16 + rr;
      f16x4 hv;
      hv[0] = (f16)tile[cc + 0][q];
      hv[1] = (f16)tile[cc + 1][q];
      hv[2] = (f16)tile[cc + 2][q];
      hv[3] = (f16)tile[cc + 3][q];
      *(f16x4*)(P0 + ((size_t)b * 2048 + q0 + q) * 4096 + plane * 2048 + n0 + cc) = hv;
    }
  }
}

// ---------------------------------------------------------------------------
// pack_w: wpk[idx].x = (wr, -wi), wpk[idx].y = (wi, wr); idx = [k][tau][ci][co]
// ---------------------------------------------------------------------------
__global__ __launch_bounds__(256) void pack_w(const float* __restrict__ wr,
                                              const float* __restrict__ wi,
                                              uint2* __restrict__ wpk) {
  int idx = blockIdx.x * 256 + threadIdx.x;
  if (idx >= Kn * TAUn * CIn * COn) return;
  float r = wr[idx], i = wi[idx];
  uint16_t hr = __builtin_bit_cast(uint16_t, (f16)r);
  uint16_t hi = __builtin_bit_cast(uint16_t, (f16)i);
  uint16_t hni = __builtin_bit_cast(uint16_t, (f16)(-i));
  uint2 o;
  o.x = (uint32_t)hr | ((uint32_t)hni << 16);
  o.y = (uint32_t)hi | ((uint32_t)hr << 16);
  wpk[idx] = o;
}

// ---------------------------------------------------------------------------
// cheb_gemm: embedded-real complex GEMM, 8-phase schedule (m201 template).
//   C[n'][j] = sum_{k'} G2[n'][k'] * P[j][k'],  n',k' in [0,4096), j in [0,8192)
//   G2 = [[Gr,-Gi],[Gi,Gr]] (negation in-register on A fragments).
// MODE 0: Q = C ; MODE 1: Q = 2C - Q (in place).
// 512 thr = 8 waves (2M x 4N); tile 256(n') x 256(j), BK=64, wave-tile 128x64.
// LDS ring: 8 x 16KB chunks. Tile kt (base=(kt&1)*4): A0=base, A1=base+1
// (128 n'-rows each), B0=base+2, B1=base+3 (128 j-rows each). Chunk-major
// internal layout [c8][row128]x16B -> conflict-free frag reads (0 measured).
// Per K-tile: 4 phases, each {ds-frag reads | 1 chunk prefetch | bar |
// setprio 16xMFMA (one 64x32 C-quadrant x K=64) | bar}. Quadrants ordered
// (0,0),(0,1),(1,1),(1,0): A reloaded at P0/P2, both B halves held in regs.
// Stage schedule: P0: A1(kt+1); P1: B0(kt+1); P2: B1(kt+1); P3: A0(kt+2).
// Slot-reuse safety: each slot rewritten >=1 phase after last read, behind a
// barrier. Gate ONCE per tile: vmcnt(2) (chunk staged at P3 stays in flight).
// Prologue = 5 chunks (t0 full + t1.A0) -> steady-state counts from kt=0.
// XCD swizzle (FETCH-proven): bj = xcd*4 + (l>>4), bn = l&15.
// ---------------------------------------------------------------------------
template <int MODE>
__global__ __launch_bounds__(512, 2) void cheb_gemm(
    const f16* __restrict__ Gr, const f16* __restrict__ Gi,
    const f16* __restrict__ P, f16* __restrict__ Q) {
  extern __shared__ __align__(16) char lds[];
  f16* L = (f16*)lds;

  const int tid = threadIdx.x;
  const int lane = tid & 63;
  const int w = tid >> 6;
  const int wm = w >> 2;              // 0..1 : 128-row n'-strip
  const int wn = w & 3;               // 0..3 : 64-row j-strip
  const int sub = lane >> 4, rr = lane & 15;

  const int bid = blockIdx.x;
  const int xcd = bid & 7;
  const int l = bid >> 3;             // 0..63 in-XCD
  const int bj = xcd * 4 + (l >> 4);
  const int bn = l & 15;
  const int n0 = bn * 256, j0 = bj * 256;
  const bool top = n0 < 2048;
  const int gmbase = n0 & 2047;

  // stage one 16KB chunk (128 rows x 64 k) = 2 gld_lds16/thread; u = c*128+row
  auto stageA = [&](const f16* plane, int kcol, int h, int slot) {
    #pragma unroll
    for (int p = 0; p < 2; ++p) {
      int u = p * 512 + tid;
      int row = u & 127, c = u >> 7;
      const f16* src = plane + (size_t)(gmbase + h * 128 + row) * 2048 + kcol + c * 8;
      gld_lds16(src, L + slot * 8192 + (u - lane) * 8);
    }
  };
  auto stageB = [&](int kt, int h, int slot) {
    #pragma unroll
    for (int p = 0; p < 2; ++p) {
      int u = p * 512 + tid;
      int row = u & 127, c = u >> 7;
      const f16* src = P + (size_t)(j0 + h * 128 + row) * 4096 + kt * 64 + c * 8;
      gld_lds16(src, L + slot * 8192 + (u - lane) * 8);
    }
  };
  auto Aplane = [&](int kt) -> const f16* {
    bool kr = (kt & 32) != 0;  // k' >= 2048
    return top ? (kr ? Gi : Gr) : (kr ? Gr : Gi);
  };

  f32x4 acc[8][4] = {};
  f16x8 afr[4][2], bfr0[2][2], bfr1[2][2];

  // prologue: t0 chunks in steady-state issue order, then t1.A0 (10 VMEM ops)
  stageA(Aplane(0), 0, 0, 0);
  stageA(Aplane(0), 0, 1, 1);
  stageB(0, 0, 2);
  stageB(0, 1, 3);
  stageA(Aplane(1), 64, 0, 4);

  for (int kt = 0; kt < 64; ++kt) {
    const int base = (kt & 1) * 4;
    const int nbase = base ^ 4;
    const int ktn = (kt + 1) & 63;   // wrap -> dummy restage, uniform counts
    const int ktn2 = (kt + 2) & 63;
    const f16* apn = Aplane(ktn);
    const f16* apn2 = Aplane(ktn2);
    const int kcoln = (ktn * 64) & 2047;
    const int kcoln2 = (ktn2 * 64) & 2047;
    const bool negA = top && (kt & 32);
    const int Aslot = base + wm;
    const int Bslot = base + 2 + (wn >> 1);
    const int brow = (wn & 1) * 64;

    auto loadA = [&](int qm) {
      #pragma unroll
      for (int f = 0; f < 4; ++f)
        #pragma unroll
        for (int ks = 0; ks < 2; ++ks)
          afr[f][ks] = *(const f16x8*)(
              L + Aslot * 8192 + ((ks * 4 + sub) * 128 + qm * 64 + f * 16 + rr) * 8);
      if (negA) {
        #pragma unroll
        for (int f = 0; f < 4; ++f) { afr[f][0] = -afr[f][0]; afr[f][1] = -afr[f][1]; }
      }
    };
    auto loadB = [&](f16x8 (&bq)[2][2], int qn) {
      #pragma unroll
      for (int fc = 0; fc < 2; ++fc)
        #pragma unroll
        for (int ks = 0; ks < 2; ++ks)
          bq[fc][ks] = *(const f16x8*)(
              L + Bslot * 8192 + ((ks * 4 + sub) * 128 + brow + qn * 32 + fc * 16 + rr) * 8);
    };
    auto mf16 = [&](f16x8 (&bq)[2][2], int accR, int accC) {
      __builtin_amdgcn_s_setprio(1);
      #pragma unroll
      for (int f = 0; f < 4; ++f)
        #pragma unroll
        for (int fc = 0; fc < 2; ++fc)
          #pragma unroll
          for (int ks = 0; ks < 2; ++ks)
            acc[accR + f][accC + fc] = __builtin_amdgcn_mfma_f32_16x16x32_f16(
                afr[f][ks], bq[fc][ks], acc[accR + f][accC + fc], 0, 0, 0);
      __builtin_amdgcn_s_setprio(0);
    };

    // boundary gate: tile kt's 4 chunks visible; only kt+1.A0 stays in flight
    asm volatile("s_waitcnt vmcnt(2)" ::: "memory");
    __builtin_amdgcn_s_barrier();

    // P0: quadrant (0,0)
    loadA(0); loadB(bfr0, 0);
    stageA(apn, kcoln, 1, nbase + 1);
    __builtin_amdgcn_s_barrier();
    mf16(bfr0, 0, 0);
    __builtin_amdgcn_s_barrier();

    // P1: quadrant (0,1)
    loadB(bfr1, 1);
    stageB(ktn, 0, nbase + 2);
    __builtin_amdgcn_s_barrier();
    mf16(bfr1, 0, 2);
    __builtin_amdgcn_s_barrier();

    // P2: quadrant (1,1)
    loadA(1);
    stageB(ktn, 1, nbase + 3);
    __builtin_amdgcn_s_barrier();
    mf16(bfr1, 4, 2);
    __builtin_amdgcn_s_barrier();

    // P3: quadrant (1,0)  (no ds reads; A(1) and B(0) already in regs)
    stageA(apn2, kcoln2, 0, base + 0);
    __builtin_amdgcn_s_barrier();
    mf16(bfr0, 4, 0);
    __builtin_amdgcn_s_barrier();
  }

  asm volatile("s_waitcnt vmcnt(0)" ::: "memory");

  // Epilogue: transposed write Q[j][n']; C/D map col=lane&15, row=(lane>>4)*4+r
  #pragma unroll
  for (int fc = 0; fc < 4; ++fc) {
    size_t j = (size_t)j0 + wn * 64 + fc * 16 + (lane & 15);
    #pragma unroll
    for (int fr = 0; fr < 8; ++fr) {
      int nn = n0 + wm * 128 + fr * 16 + ((lane >> 4) << 2);
      size_t off = j * 4096 + nn;
      f16x4 v;
      if (MODE == 1) {
        f16x4 o = *(const f16x4*)(Q + off);
        #pragma unroll
        for (int r = 0; r < 4; ++r)
          v[r] = (f16)(2.0f * acc[fr][fc][r] - (float)o[r]);
      } else {
        #pragma unroll
        for (int r = 0; r < 4; ++r)
          v[r] = (f16)acc[fr][fc][r];
      }
      *(f16x4*)(Q + off) = v;
    }
  }
}

// ---------------------------------------------------------------------------
// contract_k: out[b][n][t][o] (+)= sum_{tau,i} Re/Im( P_k[b,n,t-tau,i]*w[k,tau,i,o] )
// P combined plane: re at [j][n], im at [j][2048+n], row stride 4096.
// ---------------------------------------------------------------------------
template <bool CPLX>
__global__ __launch_bounds__(256, 4) void contract_k(
    const f16* __restrict__ Pc, const uint2* __restrict__ wpk,
    const float* __restrict__ biasr, const float* __restrict__ biasi,
    float* __restrict__ out, int k) {
  __shared__ __align__(16) uint32_t Plds[96 * 64];
  __shared__ __align__(16) uint32_t WA[96 * 32];
  __shared__ __align__(16) uint32_t WB[CPLX ? 96 * 32 : 32];

  const int t = threadIdx.x;
  const int n0 = blockIdx.x * 64;
  const int tt = blockIdx.y;
  const int b = blockIdx.z;

  #pragma unroll
  for (int it = 0; it < 3; ++it) {
    int task = it * 256 + t;
    int row = task >> 3, oc = task & 7;
    int tp = (tt - 2) * 32 + row;
    uint4 ur = {0, 0, 0, 0}, ui = {0, 0, 0, 0};
    if (tp >= 0) {
      size_t goff = ((size_t)b * 2048 + tp) * 4096 + n0 + oc * 8;
      ur = *(const uint4*)(Pc + goff);
      ui = *(const uint4*)(Pc + goff + 2048);
    }
    uint32_t* dst = &Plds[row * 64 + oc * 8];
    dst[0] = (ur.x & 0xffffu) | (ui.x << 16);
    dst[1] = (ur.x >> 16) | (ui.x & 0xffff0000u);
    dst[2] = (ur.y & 0xffffu) | (ui.y << 16);
    dst[3] = (ur.y >> 16) | (ui.y & 0xffff0000u);
    dst[4] = (ur.z & 0xffffu) | (ui.z << 16);
    dst[5] = (ur.z >> 16) | (ui.z & 0xffff0000u);
    dst[6] = (ur.w & 0xffffu) | (ui.w << 16);
    dst[7] = (ur.w >> 16) | (ui.w & 0xffff0000u);
  }
  #pragma unroll
  for (int it = 0; it < 12; ++it) {
    int idx = it * 256 + t;
    int q = idx >> 5, o = idx & 31;
    int tau = 2 - (q >> 5), ci = q & 31;
    uint2 wv = wpk[((k * TAUn + tau) * CIn + ci) * COn + o];
    WA[idx] = wv.x;
    if (CPLX) WB[idx] = wv.y;
  }
  __syncthreads();

  const int no = t & 7, ng = t >> 3;
  float aR[8] = {0, 0, 0, 0, 0, 0, 0, 0};
  float aI[8] = {0, 0, 0, 0, 0, 0, 0, 0};
  for (int q = 0; q < 96; ++q) {
    uint2 pp = *(const uint2*)&Plds[q * 64 + ng * 2];
    f16x2 h0 = __builtin_bit_cast(f16x2, pp.x);
    f16x2 h1 = __builtin_bit_cast(f16x2, pp.y);
    uint4 wa = *(const uint4*)&WA[q * 32 + no * 4];
    const uint32_t* wap = &wa.x;
    #pragma unroll
    for (int c = 0; c < 4; ++c) {
      f16x2 wv = __builtin_bit_cast(f16x2, wap[c]);
      aR[c] = fdot2(h0, wv, aR[c]);
      aR[4 + c] = fdot2(h1, wv, aR[4 + c]);
    }
    if (CPLX) {
      uint4 wb = *(const uint4*)&WB[q * 32 + no * 4];
      const uint32_t* wbp = &wb.x;
      #pragma unroll
      for (int c = 0; c < 4; ++c) {
        f16x2 wv = __builtin_bit_cast(f16x2, wbp[c]);
        aI[c] = fdot2(h0, wv, aI[c]);
        aI[4 + c] = fdot2(h1, wv, aI[4 + c]);
      }
    }
  }

  #pragma unroll
  for (int a = 0; a < 2; ++a) {
    size_t n = (size_t)n0 + ng * 2 + a;
    size_t ob = (((size_t)b * Nn + n) * Tn + tt) * COn + no * 4;
    if (!CPLX) {
      float4 v;
      v.x = aR[a * 4 + 0]; v.y = aR[a * 4 + 1];
      v.z = aR[a * 4 + 2]; v.w = aR[a * 4 + 3];
      float4 cur;
      if (k == 0) cur = *(const float4*)(biasr + no * 4);
      else cur = *(const float4*)(out + ob);
      v.x += cur.x; v.y += cur.y; v.z += cur.z; v.w += cur.w;
      *(float4*)(out + ob) = v;
    } else {
      float* po = out + ob * 2;
      float4 lo, hi;
      lo.x = aR[a * 4 + 0]; lo.y = aI[a * 4 + 0];
      lo.z = aR[a * 4 + 1]; lo.w = aI[a * 4 + 1];
      hi.x = aR[a * 4 + 2]; hi.y = aI[a * 4 + 2];
      hi.z = aR[a * 4 + 3]; hi.w = aI[a * 4 + 3];
      float4 c0, c1;
      if (k == 0) {
        const float* pr = biasr + no * 4;
        const float* pi = biasi + no * 4;
        c0 = make_float4(pr[0], pi[0], pr[1], pi[1]);
        c1 = make_float4(pr[2], pi[2], pr[3], pi[3]);
      } else {
        c0 = *(const float4*)(po);
        c1 = *(const float4*)(po + 4);
      }
      lo.x += c0.x; lo.y += c0.y; lo.z += c0.z; lo.w += c0.w;
      hi.x += c1.x; hi.y += c1.y; hi.z += c1.z; hi.w += c1.w;
      *(float4*)(po) = lo;
      *(float4*)(po + 4) = hi;
    }
  }
}

// ---------------------------------------------------------------------------
extern "C" void kernel_launch(void* const* d_in, const int* in_sizes, int n_in,
                              void* d_out, int out_size, void* d_ws, size_t ws_size,
                              hipStream_t stream) {
  (void)in_sizes; (void)n_in;
  const float* xr = (const float*)d_in[0];
  const float* xi = (const float*)d_in[1];
  const float* gr = (const float*)d_in[2];
  const float* gi = (const float*)d_in[3];
  const float* wr = (const float*)d_in[4];
  const float* wi = (const float*)d_in[5];
  const float* biasr = (const float*)d_in[6];
  const float* biasi = (const float*)d_in[7];
  float* out = (float*)d_out;

  const size_t PPLANE = (size_t)Jn * 4096 * sizeof(f16);  // 67,108,864 (combined)
  const size_t GPLANE = (size_t)Nn * Nn * sizeof(f16);    // 8,388,608
  const size_t WPK = (size_t)Kn * TAUn * CIn * COn * 8;   // 147,456
  if (ws_size < 2 * PPLANE + 2 * GPLANE + WPK) return;

  char* ws = (char*)d_ws;
  f16* P0 = (f16*)(ws);
  f16* P1 = (f16*)(ws + PPLANE);
  f16* Gr = (f16*)(ws + 2 * PPLANE);
  f16* Gi = (f16*)(ws + 2 * PPLANE + GPLANE);
  uint2* wpk = (uint2*)(ws + 2 * PPLANE + 2 * GPLANE);

  const bool cplx = (out_size == 2 * Bn * Nn * Tn * COn);

  pack_gso<<<dim3(4096), dim3(256), 0, stream>>>(gr, gi, Gr, Gi);
  pack_x<<<dim3(32, 32, 4), dim3(256), 0, stream>>>(xr, xi, P0);
  pack_w<<<dim3(72), dim3(256), 0, stream>>>(wr, wi, wpk);

  #define CONTRACT(KK, Pp)                                                         \
    do {                                                                           \
      if (cplx)                                                                    \
        contract_k<true><<<dim3(32, 64, 4), dim3(256), 0, stream>>>(               \
            Pp, wpk, biasr, biasi, out, KK);                                       \
      else                                                                         \
        contract_k<false><<<dim3(32, 64, 4), dim3(256), 0, stream>>>(              \
            Pp, wpk, biasr, biasi, out, KK);                                       \
    } while (0)

  CONTRACT(0, P0);
  cheb_gemm<0><<<dim3(512), dim3(512), 131072, stream>>>(Gr, Gi, P0, P1);
  CONTRACT(1, P1);
  cheb_gemm<1><<<dim3(512), dim3(512), 131072, stream>>>(Gr, Gi, P1, P0);
  CONTRACT(2, P0);
  cheb_gemm<1><<<dim3(512), dim3(512), 131072, stream>>>(Gr, Gi, P0, P1);
  CONTRACT(3, P1);
  cheb_gemm<1><<<dim3(512), dim3(512), 131072, stream>>>(Gr, Gi, P1, P0);
  CONTRACT(4, P0);
  cheb_gemm<1><<<dim3(512), dim3(512), 131072, stream>>>(Gr, Gi, P0, P1);
  CONTRACT(5, P1);
  #undef CONTRACT
}

// Round 8
// 1990.642 us; speedup vs baseline: 1.1453x; 1.0252x over previous
//
#include <hip/hip_runtime.h>
#include <stdint.h>

// Problem constants (ComplexChebTemporalConv)
#define Bn 4
#define Nn 2048
#define Tn 64
#define CIn 32
#define COn 32
#define Kn 6
#define TAUn 3
#define Jn 8192  // B*T*CI

typedef _Float16 f16;
typedef _Float16 f16x2 __attribute__((ext_vector_type(2)));
typedef _Float16 f16x4 __attribute__((ext_vector_type(4)));
typedef _Float16 f16x8 __attribute__((ext_vector_type(8)));
typedef float f32x4 __attribute__((ext_vector_type(4)));

template <int N> struct ic { static constexpr int v = N; };

#if defined(__has_builtin)
#if __has_builtin(__builtin_amdgcn_fdot2)
#define HAVE_FDOT2 1
#endif
#endif

__device__ __forceinline__ float fdot2(f16x2 a, f16x2 b, float c) {
#ifdef HAVE_FDOT2
  return __builtin_amdgcn_fdot2(a, b, c, false);
#else
  return c + (float)a[0] * (float)b[0] + (float)a[1] * (float)b[1];
#endif
}

__device__ __forceinline__ void gld_lds16(const void* g, void* l) {
  auto gp = (const __attribute__((address_space(1))) uint32_t*)(uintptr_t)g;
  auto lp = (__attribute__((address_space(3))) uint32_t*)(uint32_t)(uintptr_t)l;
  __builtin_amdgcn_global_load_lds(gp, lp, 16, 0, 0);
}

// ---------------------------------------------------------------------------
// pack_gso: fp32 gso planes -> f16 planes (row-major [n][m])
// ---------------------------------------------------------------------------
__global__ __launch_bounds__(256) void pack_gso(const float* __restrict__ gr,
                                                const float* __restrict__ gi,
                                                f16* __restrict__ Gr,
                                                f16* __restrict__ Gi) {
  int u = blockIdx.x * 256 + threadIdx.x;
  float4 vr = ((const float4*)gr)[u];
  float4 vi = ((const float4*)gi)[u];
  f16x4 hr, hi;
  hr[0] = (f16)vr.x; hr[1] = (f16)vr.y; hr[2] = (f16)vr.z; hr[3] = (f16)vr.w;
  hi[0] = (f16)vi.x; hi[1] = (f16)vi.y; hi[2] = (f16)vi.z; hi[3] = (f16)vi.w;
  ((f16x4*)Gr)[u] = hr;
  ((f16x4*)Gi)[u] = hi;
}

// ---------------------------------------------------------------------------
// pack_x: x [b][n][q] fp32 -> combined P0[j=b*2048+q][4096]: re at col n, im at 2048+n
// ---------------------------------------------------------------------------
__global__ __launch_bounds__(256) void pack_x(const float* __restrict__ xr,
                                              const float* __restrict__ xi,
                                              f16* __restrict__ P0) {
  __shared__ float tile[64][65];
  const int t = threadIdx.x;
  const int q0 = blockIdx.x * 64;
  const int n0 = blockIdx.y * 64;
  const int b = blockIdx.z;
  const int rr = t >> 4;
  const int cc = (t & 15) * 4;
  #pragma unroll
  for (int plane = 0; plane < 2; ++plane) {
    const float* src = plane ? xi : xr;
    if (plane) __syncthreads();
    #pragma unroll
    for (int it = 0; it < 4; ++it) {
      int n = it * 16 + rr;
      float4 v = *(const float4*)(src + ((size_t)b * Nn + n0 + n) * 2048 + q0 + cc);
      tile[n][cc + 0] = v.x; tile[n][cc + 1] = v.y;
      tile[n][cc + 2] = v.z; tile[n][cc + 3] = v.w;
    }
    __syncthreads();
    #pragma unroll
    for (int it = 0; it < 4; ++it) {
      int q = it * 16 + rr;
      f16x4 hv;
      hv[0] = (f16)tile[cc + 0][q];
      hv[1] = (f16)tile[cc + 1][q];
      hv[2] = (f16)tile[cc + 2][q];
      hv[3] = (f16)tile[cc + 3][q];
      *(f16x4*)(P0 + ((size_t)b * 2048 + q0 + q) * 4096 + plane * 2048 + n0 + cc) = hv;
    }
  }
}

// ---------------------------------------------------------------------------
// pack_w: wpk[idx].x = (wr, -wi), wpk[idx].y = (wi, wr); idx = [k][tau][ci][co]
// ---------------------------------------------------------------------------
__global__ __launch_bounds__(256) void pack_w(const float* __restrict__ wr,
                                              const float* __restrict__ wi,
                                              uint2* __restrict__ wpk) {
  int idx = blockIdx.x * 256 + threadIdx.x;
  if (idx >= Kn * TAUn * CIn * COn) return;
  float r = wr[idx], i = wi[idx];
  uint16_t hr = __builtin_bit_cast(uint16_t, (f16)r);
  uint16_t hi = __builtin_bit_cast(uint16_t, (f16)i);
  uint16_t hni = __builtin_bit_cast(uint16_t, (f16)(-i));
  uint2 o;
  o.x = (uint32_t)hr | ((uint32_t)hni << 16);
  o.y = (uint32_t)hi | ((uint32_t)hr << 16);
  wpk[idx] = o;
}

// ---------------------------------------------------------------------------
// cheb_gemm: embedded-real complex GEMM, 8-phase schedule (m201 template),
// r8 refinements: ks-outer MFMA, kt unrolled x2 (literal slots -> imm-offset
// ds_reads), deeper stage schedule with boundary gate vmcnt(4).
//   C[n'][j] = sum_{k'} G2[n'][k'] * P[j][k'];  G2 = [[Gr,-Gi],[Gi,Gr]].
// MODE 0: Q = C ; MODE 1: Q = 2C - Q (in place).
// 512 thr = 8 waves (2M x 4N); tile 256(n') x 256(j), BK=64, wave-tile 128x64.
// LDS ring: 8 x 16KB chunks; parity E: A0=E*4, A1=E*4+1, B0=E*4+2, B1=E*4+3.
// Chunk layout [c:8][pos:128]x16B, conflict-free (0 measured all rounds).
// Per tile: 4 phases {frag ds_reads | 1 chunk stage | bar | MFMA x16 | bar}.
// Stage schedule (slot-free proven): P0: A1(kt+1); P1: B1(kt+1);
// P2: B0(kt+2); P3: A0(kt+2).  A slots dead after P2, B slots after P1;
// every overwrite >=1 barrier after last read's lgkm retire.
// Gate once per tile: vmcnt(4) -- queue at gate(kt), oldest first:
// B0(kt),A0(kt),A1(kt),B1(kt) | B0(kt+1),A0(kt+1) (2 chunks=4 ops in flight).
// Prologue stages exactly that queue order (6 chunks).
// XCD swizzle (FETCH-proven): bj = xcd*4 + (l>>4), bn = l&15.
// ---------------------------------------------------------------------------
template <int MODE>
__global__ __launch_bounds__(512, 2) void cheb_gemm(
    const f16* __restrict__ Gr, const f16* __restrict__ Gi,
    const f16* __restrict__ P, f16* __restrict__ Q) {
  extern __shared__ __align__(16) char lds[];
  f16* L = (f16*)lds;

  const int tid = threadIdx.x;
  const int lane = tid & 63;
  const int w = tid >> 6;
  const int wm = w >> 2;              // 0..1 : 128-row n'-strip
  const int wn = w & 3;               // 0..3 : 64-row j-strip
  const int sub = lane >> 4, rr = lane & 15;

  const int bid = blockIdx.x;
  const int xcd = bid & 7;
  const int l = bid >> 3;             // 0..63 in-XCD
  const int bj = xcd * 4 + (l >> 4);
  const int bn = l & 15;
  const int n0 = bn * 256, j0 = bj * 256;
  const bool top = n0 < 2048;
  const int gmbase = n0 & 2047;

  // ---- hoisted per-thread invariants ----
  // frag-read offsets (elements): chunk[c=ks*4+sub][pos]*8
  const int aofs = sub * 1024 + rr * 8;                    // + ks*4096 + qm*512 + f*128
  const int bofs = sub * 1024 + (wn & 1) * 512 + rr * 8;   // + ks*4096 + qn*256 + fc*128
  // staging: per-thread global offsets and LDS dest
  const int srow = tid & 127, scol = (tid >> 7) * 8;
  const size_t aoffg = (size_t)(gmbase + srow) * 2048 + scol;
  const size_t boffg = (size_t)(j0 + srow) * 4096 + scol;
  const int sdst = (tid - lane) * 8;                       // + p*4096

  auto stageA = [&](const f16* plane, int kcol, int h, int slot) {
    #pragma unroll
    for (int p = 0; p < 2; ++p)
      gld_lds16(plane + aoffg + h * 262144 + kcol + p * 32,
                L + slot * 8192 + sdst + p * 4096);
  };
  auto stageB = [&](int kt_, int h, int slot) {
    #pragma unroll
    for (int p = 0; p < 2; ++p)
      gld_lds16(P + boffg + h * 524288 + kt_ * 64 + p * 32,
                L + slot * 8192 + sdst + p * 4096);
  };
  auto Aplane = [&](int kt_) -> const f16* {
    bool kr = (kt_ & 32) != 0;  // k' >= 2048
    return top ? (kr ? Gi : Gr) : (kr ? Gr : Gi);
  };

  f32x4 acc[8][4] = {};
  f16x8 afr[4][2], bfr0[2][2], bfr1[2][2];

  // prologue: 6 chunks in steady-state queue order
  stageB(0, 0, 2);             // B0(0)
  stageA(Aplane(0), 0, 0, 0);  // A0(0)
  stageA(Aplane(0), 0, 1, 1);  // A1(0)
  stageB(0, 1, 3);             // B1(0)
  stageB(1, 0, 6);             // B0(1)
  stageA(Aplane(1), 64, 0, 4); // A0(1)

  for (int k2 = 0; k2 < 32; ++k2) {
    const int ktb = k2 * 2;

    auto tile = [&](auto ec) {
      constexpr int E = decltype(ec)::v;
      const int kt = ktb + E;
      const int ktn = (kt + 1) & 63;    // wrap -> dummy restage, uniform counts
      const int ktn2 = (kt + 2) & 63;
      const f16* apn = Aplane(ktn);
      const f16* apn2 = Aplane(ktn2);
      const int kcoln = (ktn * 64) & 2047;
      const int kcoln2 = (ktn2 * 64) & 2047;
      const bool negA = top && (kt & 32);

      auto loadA = [&](int qm) {
        #pragma unroll
        for (int f = 0; f < 4; ++f)
          #pragma unroll
          for (int ks = 0; ks < 2; ++ks)
            afr[f][ks] = *(const f16x8*)(
                L + (E * 4 + wm) * 8192 + aofs + ks * 4096 + qm * 512 + f * 128);
        if (negA) {
          #pragma unroll
          for (int f = 0; f < 4; ++f) { afr[f][0] = -afr[f][0]; afr[f][1] = -afr[f][1]; }
        }
      };
      auto loadB = [&](f16x8 (&bq)[2][2], int qn) {
        #pragma unroll
        for (int fc = 0; fc < 2; ++fc)
          #pragma unroll
          for (int ks = 0; ks < 2; ++ks)
            bq[fc][ks] = *(const f16x8*)(
                L + (E * 4 + 2 + (wn >> 1)) * 8192 + bofs + ks * 4096 + qn * 256 + fc * 128);
      };
      auto mf16 = [&](f16x8 (&bq)[2][2], int accR, int accC) {
        __builtin_amdgcn_s_setprio(1);
        #pragma unroll
        for (int ks = 0; ks < 2; ++ks)     // ks OUTER: 8 independent MFMA per pass
          #pragma unroll
          for (int f = 0; f < 4; ++f)
            #pragma unroll
            for (int fc = 0; fc < 2; ++fc)
              acc[accR + f][accC + fc] = __builtin_amdgcn_mfma_f32_16x16x32_f16(
                  afr[f][ks], bq[fc][ks], acc[accR + f][accC + fc], 0, 0, 0);
        __builtin_amdgcn_s_setprio(0);
      };

      // boundary gate: tile kt's 4 chunks visible; B0/A0(kt+1) stay in flight
      asm volatile("s_waitcnt vmcnt(4)" ::: "memory");
      __builtin_amdgcn_s_barrier();

      // P0: quadrant (0,0)
      loadA(0); loadB(bfr0, 0);
      stageA(apn, kcoln, 1, (E ^ 1) * 4 + 1);
      __builtin_amdgcn_s_barrier();
      mf16(bfr0, 0, 0);
      __builtin_amdgcn_s_barrier();

      // P1: quadrant (0,1)
      loadB(bfr1, 1);
      stageB(ktn, 1, (E ^ 1) * 4 + 3);
      __builtin_amdgcn_s_barrier();
      mf16(bfr1, 0, 2);
      __builtin_amdgcn_s_barrier();

      // P2: quadrant (1,1)
      loadA(1);
      stageB(ktn2, 0, E * 4 + 2);
      __builtin_amdgcn_s_barrier();
      mf16(bfr1, 4, 2);
      __builtin_amdgcn_s_barrier();

      // P3: quadrant (1,0)
      stageA(apn2, kcoln2, 0, E * 4 + 0);
      __builtin_amdgcn_s_barrier();
      mf16(bfr0, 4, 0);
      __builtin_amdgcn_s_barrier();
    };

    tile(ic<0>{});
    tile(ic<1>{});
  }

  asm volatile("s_waitcnt vmcnt(0)" ::: "memory");

  // Epilogue: transposed write Q[j][n']; C/D map col=lane&15, row=(lane>>4)*4+r
  #pragma unroll
  for (int fc = 0; fc < 4; ++fc) {
    size_t j = (size_t)j0 + wn * 64 + fc * 16 + (lane & 15);
    #pragma unroll
    for (int fr = 0; fr < 8; ++fr) {
      int nn = n0 + wm * 128 + fr * 16 + ((lane >> 4) << 2);
      size_t off = j * 4096 + nn;
      f16x4 v;
      if (MODE == 1) {
        f16x4 o = *(const f16x4*)(Q + off);
        #pragma unroll
        for (int r = 0; r < 4; ++r)
          v[r] = (f16)(2.0f * acc[fr][fc][r] - (float)o[r]);
      } else {
        #pragma unroll
        for (int r = 0; r < 4; ++r)
          v[r] = (f16)acc[fr][fc][r];
      }
      *(f16x4*)(Q + off) = v;
    }
  }
}

// ---------------------------------------------------------------------------
// contract_k: out[b][n][t][o] (+)= sum_{tau,i} Re/Im( P_k[b,n,t-tau,i]*w[k,tau,i,o] )
// P combined plane: re at [j][n], im at [j][2048+n], row stride 4096.
// ---------------------------------------------------------------------------
template <bool CPLX>
__global__ __launch_bounds__(256, 4) void contract_k(
    const f16* __restrict__ Pc, const uint2* __restrict__ wpk,
    const float* __restrict__ biasr, const float* __restrict__ biasi,
    float* __restrict__ out, int k) {
  __shared__ __align__(16) uint32_t Plds[96 * 64];
  __shared__ __align__(16) uint32_t WA[96 * 32];
  __shared__ __align__(16) uint32_t WB[CPLX ? 96 * 32 : 32];

  const int t = threadIdx.x;
  const int n0 = blockIdx.x * 64;
  const int tt = blockIdx.y;
  const int b = blockIdx.z;

  #pragma unroll
  for (int it = 0; it < 3; ++it) {
    int task = it * 256 + t;
    int row = task >> 3, oc = task & 7;
    int tp = (tt - 2) * 32 + row;
    uint4 ur = {0, 0, 0, 0}, ui = {0, 0, 0, 0};
    if (tp >= 0) {
      size_t goff = ((size_t)b * 2048 + tp) * 4096 + n0 + oc * 8;
      ur = *(const uint4*)(Pc + goff);
      ui = *(const uint4*)(Pc + goff + 2048);
    }
    uint32_t* dst = &Plds[row * 64 + oc * 8];
    dst[0] = (ur.x & 0xffffu) | (ui.x << 16);
    dst[1] = (ur.x >> 16) | (ui.x & 0xffff0000u);
    dst[2] = (ur.y & 0xffffu) | (ui.y << 16);
    dst[3] = (ur.y >> 16) | (ui.y & 0xffff0000u);
    dst[4] = (ur.z & 0xffffu) | (ui.z << 16);
    dst[5] = (ur.z >> 16) | (ui.z & 0xffff0000u);
    dst[6] = (ur.w & 0xffffu) | (ui.w << 16);
    dst[7] = (ur.w >> 16) | (ui.w & 0xffff0000u);
  }
  #pragma unroll
  for (int it = 0; it < 12; ++it) {
    int idx = it * 256 + t;
    int q = idx >> 5, o = idx & 31;
    int tau = 2 - (q >> 5), ci = q & 31;
    uint2 wv = wpk[((k * TAUn + tau) * CIn + ci) * COn + o];
    WA[idx] = wv.x;
    if (CPLX) WB[idx] = wv.y;
  }
  __syncthreads();

  const int no = t & 7, ng = t >> 3;
  float aR[8] = {0, 0, 0, 0, 0, 0, 0, 0};
  float aI[8] = {0, 0, 0, 0, 0, 0, 0, 0};
  for (int q = 0; q < 96; ++q) {
    uint2 pp = *(const uint2*)&Plds[q * 64 + ng * 2];
    f16x2 h0 = __builtin_bit_cast(f16x2, pp.x);
    f16x2 h1 = __builtin_bit_cast(f16x2, pp.y);
    uint4 wa = *(const uint4*)&WA[q * 32 + no * 4];
    const uint32_t* wap = &wa.x;
    #pragma unroll
    for (int c = 0; c < 4; ++c) {
      f16x2 wv = __builtin_bit_cast(f16x2, wap[c]);
      aR[c] = fdot2(h0, wv, aR[c]);
      aR[4 + c] = fdot2(h1, wv, aR[4 + c]);
    }
    if (CPLX) {
      uint4 wb = *(const uint4*)&WB[q * 32 + no * 4];
      const uint32_t* wbp = &wb.x;
      #pragma unroll
      for (int c = 0; c < 4; ++c) {
        f16x2 wv = __builtin_bit_cast(f16x2, wbp[c]);
        aI[c] = fdot2(h0, wv, aI[c]);
        aI[4 + c] = fdot2(h1, wv, aI[4 + c]);
      }
    }
  }

  #pragma unroll
  for (int a = 0; a < 2; ++a) {
    size_t n = (size_t)n0 + ng * 2 + a;
    size_t ob = (((size_t)b * Nn + n) * Tn + tt) * COn + no * 4;
    if (!CPLX) {
      float4 v;
      v.x = aR[a * 4 + 0]; v.y = aR[a * 4 + 1];
      v.z = aR[a * 4 + 2]; v.w = aR[a * 4 + 3];
      float4 cur;
      if (k == 0) cur = *(const float4*)(biasr + no * 4);
      else cur = *(const float4*)(out + ob);
      v.x += cur.x; v.y += cur.y; v.z += cur.z; v.w += cur.w;
      *(float4*)(out + ob) = v;
    } else {
      float* po = out + ob * 2;
      float4 lo, hi;
      lo.x = aR[a * 4 + 0]; lo.y = aI[a * 4 + 0];
      lo.z = aR[a * 4 + 1]; lo.w = aI[a * 4 + 1];
      hi.x = aR[a * 4 + 2]; hi.y = aI[a * 4 + 2];
      hi.z = aR[a * 4 + 3]; hi.w = aI[a * 4 + 3];
      float4 c0, c1;
      if (k == 0) {
        const float* pr = biasr + no * 4;
        const float* pi = biasi + no * 4;
        c0 = make_float4(pr[0], pi[0], pr[1], pi[1]);
        c1 = make_float4(pr[2], pi[2], pr[3], pi[3]);
      } else {
        c0 = *(const float4*)(po);
        c1 = *(const float4*)(po + 4);
      }
      lo.x += c0.x; lo.y += c0.y; lo.z += c0.z; lo.w += c0.w;
      hi.x += c1.x; hi.y += c1.y; hi.z += c1.z; hi.w += c1.w;
      *(float4*)(po) = lo;
      *(float4*)(po + 4) = hi;
    }
  }
}

// ---------------------------------------------------------------------------
extern "C" void kernel_launch(void* const* d_in, const int* in_sizes, int n_in,
                              void* d_out, int out_size, void* d_ws, size_t ws_size,
                              hipStream_t stream) {
  (void)in_sizes; (void)n_in;
  const float* xr = (const float*)d_in[0];
  const float* xi = (const float*)d_in[1];
  const float* gr = (const float*)d_in[2];
  const float* gi = (const float*)d_in[3];
  const float* wr = (const float*)d_in[4];
  const float* wi = (const float*)d_in[5];
  const float* biasr = (const float*)d_in[6];
  const float* biasi = (const float*)d_in[7];
  float* out = (float*)d_out;

  const size_t PPLANE = (size_t)Jn * 4096 * sizeof(f16);  // 67,108,864 (combined)
  const size_t GPLANE = (size_t)Nn * Nn * sizeof(f16);    // 8,388,608
  const size_t WPK = (size_t)Kn * TAUn * CIn * COn * 8;   // 147,456
  if (ws_size < 2 * PPLANE + 2 * GPLANE + WPK) return;

  char* ws = (char*)d_ws;
  f16* P0 = (f16*)(ws);
  f16* P1 = (f16*)(ws + PPLANE);
  f16* Gr = (f16*)(ws + 2 * PPLANE);
  f16* Gi = (f16*)(ws + 2 * PPLANE + GPLANE);
  uint2* wpk = (uint2*)(ws + 2 * PPLANE + 2 * GPLANE);

  const bool cplx = (out_size == 2 * Bn * Nn * Tn * COn);

  pack_gso<<<dim3(4096), dim3(256), 0, stream>>>(gr, gi, Gr, Gi);
  pack_x<<<dim3(32, 32, 4), dim3(256), 0, stream>>>(xr, xi, P0);
  pack_w<<<dim3(72), dim3(256), 0, stream>>>(wr, wi, wpk);

  #define CONTRACT(KK, Pp)                                                         \
    do {                                                                           \
      if (cplx)                                                                    \
        contract_k<true><<<dim3(32, 64, 4), dim3(256), 0, stream>>>(               \
            Pp, wpk, biasr, biasi, out, KK);                                       \
      else                                                                         \
        contract_k<false><<<dim3(32, 64, 4), dim3(256), 0, stream>>>(              \
            Pp, wpk, biasr, biasi, out, KK);                                       \
    } while (0)

  CONTRACT(0, P0);
  cheb_gemm<0><<<dim3(512), dim3(512), 131072, stream>>>(Gr, Gi, P0, P1);
  CONTRACT(1, P1);
  cheb_gemm<1><<<dim3(512), dim3(512), 131072, stream>>>(Gr, Gi, P1, P0);
  CONTRACT(2, P0);
  cheb_gemm<1><<<dim3(512), dim3(512), 131072, stream>>>(Gr, Gi, P0, P1);
  CONTRACT(3, P1);
  cheb_gemm<1><<<dim3(512), dim3(512), 131072, stream>>>(Gr, Gi, P1, P0);
  CONTRACT(4, P0);
  cheb_gemm<1><<<dim3(512), dim3(512), 131072, stream>>>(Gr, Gi, P0, P1);
  CONTRACT(5, P1);
  #undef CONTRACT
}

// Round 9
// 1949.989 us; speedup vs baseline: 1.1691x; 1.0208x over previous
//
#include <hip/hip_runtime.h>
#include <stdint.h>

// Problem constants (ComplexChebTemporalConv)
#define Bn 4
#define Nn 2048
#define Tn 64
#define CIn 32
#define COn 32
#define Kn 6
#define TAUn 3
#define Jn 8192  // B*T*CI

typedef _Float16 f16;
typedef _Float16 f16x2 __attribute__((ext_vector_type(2)));
typedef _Float16 f16x4 __attribute__((ext_vector_type(4)));
typedef _Float16 f16x8 __attribute__((ext_vector_type(8)));
typedef float f32x4 __attribute__((ext_vector_type(4)));

template <int N> struct ic { static constexpr int v = N; };

#if defined(__has_builtin)
#if __has_builtin(__builtin_amdgcn_fdot2)
#define HAVE_FDOT2 1
#endif
#endif

__device__ __forceinline__ float fdot2(f16x2 a, f16x2 b, float c) {
#ifdef HAVE_FDOT2
  return __builtin_amdgcn_fdot2(a, b, c, false);
#else
  return c + (float)a[0] * (float)b[0] + (float)a[1] * (float)b[1];
#endif
}

__device__ __forceinline__ void gld_lds16(const void* g, void* l) {
  auto gp = (const __attribute__((address_space(1))) uint32_t*)(uintptr_t)g;
  auto lp = (__attribute__((address_space(3))) uint32_t*)(uint32_t)(uintptr_t)l;
  __builtin_amdgcn_global_load_lds(gp, lp, 16, 0, 0);
}

// ---------------------------------------------------------------------------
// pack_gso: fp32 gso planes -> f16 planes (row-major [n][m])
// ---------------------------------------------------------------------------
__global__ __launch_bounds__(256) void pack_gso(const float* __restrict__ gr,
                                                const float* __restrict__ gi,
                                                f16* __restrict__ Gr,
                                                f16* __restrict__ Gi) {
  int u = blockIdx.x * 256 + threadIdx.x;
  float4 vr = ((const float4*)gr)[u];
  float4 vi = ((const float4*)gi)[u];
  f16x4 hr, hi;
  hr[0] = (f16)vr.x; hr[1] = (f16)vr.y; hr[2] = (f16)vr.z; hr[3] = (f16)vr.w;
  hi[0] = (f16)vi.x; hi[1] = (f16)vi.y; hi[2] = (f16)vi.z; hi[3] = (f16)vi.w;
  ((f16x4*)Gr)[u] = hr;
  ((f16x4*)Gi)[u] = hi;
}

// ---------------------------------------------------------------------------
// pack_x: x [b][n][q] fp32 -> combined P0[j=b*2048+q][4096]: re at col n, im at 2048+n
// ---------------------------------------------------------------------------
__global__ __launch_bounds__(256) void pack_x(const float* __restrict__ xr,
                                              const float* __restrict__ xi,
                                              f16* __restrict__ P0) {
  __shared__ float tile[64][65];
  const int t = threadIdx.x;
  const int q0 = blockIdx.x * 64;
  const int n0 = blockIdx.y * 64;
  const int b = blockIdx.z;
  const int rr = t >> 4;
  const int cc = (t & 15) * 4;
  #pragma unroll
  for (int plane = 0; plane < 2; ++plane) {
    const float* src = plane ? xi : xr;
    if (plane) __syncthreads();
    #pragma unroll
    for (int it = 0; it < 4; ++it) {
      int n = it * 16 + rr;
      float4 v = *(const float4*)(src + ((size_t)b * Nn + n0 + n) * 2048 + q0 + cc);
      tile[n][cc + 0] = v.x; tile[n][cc + 1] = v.y;
      tile[n][cc + 2] = v.z; tile[n][cc + 3] = v.w;
    }
    __syncthreads();
    #pragma unroll
    for (int it = 0; it < 4; ++it) {
      int q = it * 16 + rr;
      f16x4 hv;
      hv[0] = (f16)tile[cc + 0][q];
      hv[1] = (f16)tile[cc + 1][q];
      hv[2] = (f16)tile[cc + 2][q];
      hv[3] = (f16)tile[cc + 3][q];
      *(f16x4*)(P0 + ((size_t)b * 2048 + q0 + q) * 4096 + plane * 2048 + n0 + cc) = hv;
    }
  }
}

// ---------------------------------------------------------------------------
// pack_w: wpk[idx].x = (wr, -wi), wpk[idx].y = (wi, wr); idx = [k][tau][ci][co]
// ---------------------------------------------------------------------------
__global__ __launch_bounds__(256) void pack_w(const float* __restrict__ wr,
                                              const float* __restrict__ wi,
                                              uint2* __restrict__ wpk) {
  int idx = blockIdx.x * 256 + threadIdx.x;
  if (idx >= Kn * TAUn * CIn * COn) return;
  float r = wr[idx], i = wi[idx];
  uint16_t hr = __builtin_bit_cast(uint16_t, (f16)r);
  uint16_t hi = __builtin_bit_cast(uint16_t, (f16)i);
  uint16_t hni = __builtin_bit_cast(uint16_t, (f16)(-i));
  uint2 o;
  o.x = (uint32_t)hr | ((uint32_t)hni << 16);
  o.y = (uint32_t)hi | ((uint32_t)hr << 16);
  wpk[idx] = o;
}

// ---------------------------------------------------------------------------
// cheb_gemm: embedded-real complex GEMM, 8-phase schedule, r9 change:
// post-MFMA barriers REMOVED (5 barriers/K-tile: 4 pre-MFMA + gate).
// Cross-wave overlap: wave Y's phase p+1 ds_reads run while wave X still
// MFMAs phase p.  Correctness without post-MFMA barriers:
//  RAW (stage->read): gate vmcnt(4)+barrier publishes tile kt's 4 chunks.
//  WAR (read->stage): every tile-kt stage overwrites a slot whose last LDS
//   read (tile kt-1) feeds an MFMA preceding all tile-kt barriers in program
//   order; in-order issue => barrier arrival => MFMA issued => lgkm passed
//   => reads retired.  (Checked per-slot: A0@P0, A1@P2, B0@P0, B1@P1.)
//   C[n'][j] = sum_{k'} G2[n'][k'] * P[j][k'];  G2 = [[Gr,-Gi],[Gi,Gr]].
// MODE 0: Q = C ; MODE 1: Q = 2C - Q (in place).
// 512 thr = 8 waves (2M x 4N); tile 256(n') x 256(j), BK=64, wave-tile 128x64.
// LDS ring: 8 x 16KB chunks; parity E: A0=E*4, A1=E*4+1, B0=E*4+2, B1=E*4+3.
// Chunk layout [c:8][pos:128]x16B, conflict-free (0 measured all rounds).
// Stage schedule: P0: A1(kt+1); P1: B1(kt+1); P2: B0(kt+2); P3: A0(kt+2).
// Gate once per tile: vmcnt(4) -- queue oldest-first at gate(kt):
// B0(kt),A0(kt),A1(kt),B1(kt) | B0(kt+1),A0(kt+1).
// Prologue stages exactly that queue order (6 chunks).
// XCD swizzle (FETCH-proven): bj = xcd*4 + (l>>4), bn = l&15.
// ---------------------------------------------------------------------------
template <int MODE>
__global__ __launch_bounds__(512, 2) void cheb_gemm(
    const f16* __restrict__ Gr, const f16* __restrict__ Gi,
    const f16* __restrict__ P, f16* __restrict__ Q) {
  extern __shared__ __align__(16) char lds[];
  f16* L = (f16*)lds;

  const int tid = threadIdx.x;
  const int lane = tid & 63;
  const int w = tid >> 6;
  const int wm = w >> 2;              // 0..1 : 128-row n'-strip
  const int wn = w & 3;               // 0..3 : 64-row j-strip
  const int sub = lane >> 4, rr = lane & 15;

  const int bid = blockIdx.x;
  const int xcd = bid & 7;
  const int l = bid >> 3;             // 0..63 in-XCD
  const int bj = xcd * 4 + (l >> 4);
  const int bn = l & 15;
  const int n0 = bn * 256, j0 = bj * 256;
  const bool top = n0 < 2048;
  const int gmbase = n0 & 2047;

  // ---- hoisted per-thread invariants ----
  const int aofs = sub * 1024 + rr * 8;                    // + ks*4096 + qm*512 + f*128
  const int bofs = sub * 1024 + (wn & 1) * 512 + rr * 8;   // + ks*4096 + qn*256 + fc*128
  const int srow = tid & 127, scol = (tid >> 7) * 8;
  const size_t aoffg = (size_t)(gmbase + srow) * 2048 + scol;
  const size_t boffg = (size_t)(j0 + srow) * 4096 + scol;
  const int sdst = (tid - lane) * 8;                       // + p*4096

  auto stageA = [&](const f16* plane, int kcol, int h, int slot) {
    #pragma unroll
    for (int p = 0; p < 2; ++p)
      gld_lds16(plane + aoffg + h * 262144 + kcol + p * 32,
                L + slot * 8192 + sdst + p * 4096);
  };
  auto stageB = [&](int kt_, int h, int slot) {
    #pragma unroll
    for (int p = 0; p < 2; ++p)
      gld_lds16(P + boffg + h * 524288 + kt_ * 64 + p * 32,
                L + slot * 8192 + sdst + p * 4096);
  };
  auto Aplane = [&](int kt_) -> const f16* {
    bool kr = (kt_ & 32) != 0;  // k' >= 2048
    return top ? (kr ? Gi : Gr) : (kr ? Gr : Gi);
  };

  f32x4 acc[8][4] = {};
  f16x8 afr[4][2], bfr0[2][2], bfr1[2][2];

  // prologue: 6 chunks in steady-state queue order
  stageB(0, 0, 2);             // B0(0)
  stageA(Aplane(0), 0, 0, 0);  // A0(0)
  stageA(Aplane(0), 0, 1, 1);  // A1(0)
  stageB(0, 1, 3);             // B1(0)
  stageB(1, 0, 6);             // B0(1)
  stageA(Aplane(1), 64, 0, 4); // A0(1)

  for (int k2 = 0; k2 < 32; ++k2) {
    const int ktb = k2 * 2;

    auto tile = [&](auto ec) {
      constexpr int E = decltype(ec)::v;
      const int kt = ktb + E;
      const int ktn = (kt + 1) & 63;    // wrap -> dummy restage, uniform counts
      const int ktn2 = (kt + 2) & 63;
      const f16* apn = Aplane(ktn);
      const f16* apn2 = Aplane(ktn2);
      const int kcoln = (ktn * 64) & 2047;
      const int kcoln2 = (ktn2 * 64) & 2047;
      const bool negA = top && (kt & 32);

      auto loadA = [&](int qm) {
        #pragma unroll
        for (int f = 0; f < 4; ++f)
          #pragma unroll
          for (int ks = 0; ks < 2; ++ks)
            afr[f][ks] = *(const f16x8*)(
                L + (E * 4 + wm) * 8192 + aofs + ks * 4096 + qm * 512 + f * 128);
        if (negA) {
          #pragma unroll
          for (int f = 0; f < 4; ++f) { afr[f][0] = -afr[f][0]; afr[f][1] = -afr[f][1]; }
        }
      };
      auto loadB = [&](f16x8 (&bq)[2][2], int qn) {
        #pragma unroll
        for (int fc = 0; fc < 2; ++fc)
          #pragma unroll
          for (int ks = 0; ks < 2; ++ks)
            bq[fc][ks] = *(const f16x8*)(
                L + (E * 4 + 2 + (wn >> 1)) * 8192 + bofs + ks * 4096 + qn * 256 + fc * 128);
      };
      auto mf16 = [&](f16x8 (&bq)[2][2], int accR, int accC) {
        __builtin_amdgcn_s_setprio(1);
        #pragma unroll
        for (int ks = 0; ks < 2; ++ks)     // ks OUTER: 8 independent MFMA per pass
          #pragma unroll
          for (int f = 0; f < 4; ++f)
            #pragma unroll
            for (int fc = 0; fc < 2; ++fc)
              acc[accR + f][accC + fc] = __builtin_amdgcn_mfma_f32_16x16x32_f16(
                  afr[f][ks], bq[fc][ks], acc[accR + f][accC + fc], 0, 0, 0);
        __builtin_amdgcn_s_setprio(0);
      };

      // boundary gate: tile kt's 4 chunks visible; B0/A0(kt+1) stay in flight
      asm volatile("s_waitcnt vmcnt(4)" ::: "memory");
      __builtin_amdgcn_s_barrier();

      // P0: quadrant (0,0)
      loadA(0); loadB(bfr0, 0);
      stageA(apn, kcoln, 1, (E ^ 1) * 4 + 1);
      __builtin_amdgcn_s_barrier();
      mf16(bfr0, 0, 0);

      // P1: quadrant (0,1)
      loadB(bfr1, 1);
      stageB(ktn, 1, (E ^ 1) * 4 + 3);
      __builtin_amdgcn_s_barrier();
      mf16(bfr1, 0, 2);

      // P2: quadrant (1,1)
      loadA(1);
      stageB(ktn2, 0, E * 4 + 2);
      __builtin_amdgcn_s_barrier();
      mf16(bfr1, 4, 2);

      // P3: quadrant (1,0)
      stageA(apn2, kcoln2, 0, E * 4 + 0);
      __builtin_amdgcn_s_barrier();
      mf16(bfr0, 4, 0);
    };

    tile(ic<0>{});
    tile(ic<1>{});
  }

  asm volatile("s_waitcnt vmcnt(0)" ::: "memory");

  // Epilogue: transposed write Q[j][n']; C/D map col=lane&15, row=(lane>>4)*4+r
  #pragma unroll
  for (int fc = 0; fc < 4; ++fc) {
    size_t j = (size_t)j0 + wn * 64 + fc * 16 + (lane & 15);
    #pragma unroll
    for (int fr = 0; fr < 8; ++fr) {
      int nn = n0 + wm * 128 + fr * 16 + ((lane >> 4) << 2);
      size_t off = j * 4096 + nn;
      f16x4 v;
      if (MODE == 1) {
        f16x4 o = *(const f16x4*)(Q + off);
        #pragma unroll
        for (int r = 0; r < 4; ++r)
          v[r] = (f16)(2.0f * acc[fr][fc][r] - (float)o[r]);
      } else {
        #pragma unroll
        for (int r = 0; r < 4; ++r)
          v[r] = (f16)acc[fr][fc][r];
      }
      *(f16x4*)(Q + off) = v;
    }
  }
}

// ---------------------------------------------------------------------------
// contract_k: out[b][n][t][o] (+)= sum_{tau,i} Re/Im( P_k[b,n,t-tau,i]*w[k,tau,i,o] )
// P combined plane: re at [j][n], im at [j][2048+n], row stride 4096.
// ---------------------------------------------------------------------------
template <bool CPLX>
__global__ __launch_bounds__(256, 4) void contract_k(
    const f16* __restrict__ Pc, const uint2* __restrict__ wpk,
    const float* __restrict__ biasr, const float* __restrict__ biasi,
    float* __restrict__ out, int k) {
  __shared__ __align__(16) uint32_t Plds[96 * 64];
  __shared__ __align__(16) uint32_t WA[96 * 32];
  __shared__ __align__(16) uint32_t WB[CPLX ? 96 * 32 : 32];

  const int t = threadIdx.x;
  const int n0 = blockIdx.x * 64;
  const int tt = blockIdx.y;
  const int b = blockIdx.z;

  #pragma unroll
  for (int it = 0; it < 3; ++it) {
    int task = it * 256 + t;
    int row = task >> 3, oc = task & 7;
    int tp = (tt - 2) * 32 + row;
    uint4 ur = {0, 0, 0, 0}, ui = {0, 0, 0, 0};
    if (tp >= 0) {
      size_t goff = ((size_t)b * 2048 + tp) * 4096 + n0 + oc * 8;
      ur = *(const uint4*)(Pc + goff);
      ui = *(const uint4*)(Pc + goff + 2048);
    }
    uint32_t* dst = &Plds[row * 64 + oc * 8];
    dst[0] = (ur.x & 0xffffu) | (ui.x << 16);
    dst[1] = (ur.x >> 16) | (ui.x & 0xffff0000u);
    dst[2] = (ur.y & 0xffffu) | (ui.y << 16);
    dst[3] = (ur.y >> 16) | (ui.y & 0xffff0000u);
    dst[4] = (ur.z & 0xffffu) | (ui.z << 16);
    dst[5] = (ur.z >> 16) | (ui.z & 0xffff0000u);
    dst[6] = (ur.w & 0xffffu) | (ui.w << 16);
    dst[7] = (ur.w >> 16) | (ui.w & 0xffff0000u);
  }
  #pragma unroll
  for (int it = 0; it < 12; ++it) {
    int idx = it * 256 + t;
    int q = idx >> 5, o = idx & 31;
    int tau = 2 - (q >> 5), ci = q & 31;
    uint2 wv = wpk[((k * TAUn + tau) * CIn + ci) * COn + o];
    WA[idx] = wv.x;
    if (CPLX) WB[idx] = wv.y;
  }
  __syncthreads();

  const int no = t & 7, ng = t >> 3;
  float aR[8] = {0, 0, 0, 0, 0, 0, 0, 0};
  float aI[8] = {0, 0, 0, 0, 0, 0, 0, 0};
  for (int q = 0; q < 96; ++q) {
    uint2 pp = *(const uint2*)&Plds[q * 64 + ng * 2];
    f16x2 h0 = __builtin_bit_cast(f16x2, pp.x);
    f16x2 h1 = __builtin_bit_cast(f16x2, pp.y);
    uint4 wa = *(const uint4*)&WA[q * 32 + no * 4];
    const uint32_t* wap = &wa.x;
    #pragma unroll
    for (int c = 0; c < 4; ++c) {
      f16x2 wv = __builtin_bit_cast(f16x2, wap[c]);
      aR[c] = fdot2(h0, wv, aR[c]);
      aR[4 + c] = fdot2(h1, wv, aR[4 + c]);
    }
    if (CPLX) {
      uint4 wb = *(const uint4*)&WB[q * 32 + no * 4];
      const uint32_t* wbp = &wb.x;
      #pragma unroll
      for (int c = 0; c < 4; ++c) {
        f16x2 wv = __builtin_bit_cast(f16x2, wbp[c]);
        aI[c] = fdot2(h0, wv, aI[c]);
        aI[4 + c] = fdot2(h1, wv, aI[4 + c]);
      }
    }
  }

  #pragma unroll
  for (int a = 0; a < 2; ++a) {
    size_t n = (size_t)n0 + ng * 2 + a;
    size_t ob = (((size_t)b * Nn + n) * Tn + tt) * COn + no * 4;
    if (!CPLX) {
      float4 v;
      v.x = aR[a * 4 + 0]; v.y = aR[a * 4 + 1];
      v.z = aR[a * 4 + 2]; v.w = aR[a * 4 + 3];
      float4 cur;
      if (k == 0) cur = *(const float4*)(biasr + no * 4);
      else cur = *(const float4*)(out + ob);
      v.x += cur.x; v.y += cur.y; v.z += cur.z; v.w += cur.w;
      *(float4*)(out + ob) = v;
    } else {
      float* po = out + ob * 2;
      float4 lo, hi;
      lo.x = aR[a * 4 + 0]; lo.y = aI[a * 4 + 0];
      lo.z = aR[a * 4 + 1]; lo.w = aI[a * 4 + 1];
      hi.x = aR[a * 4 + 2]; hi.y = aI[a * 4 + 2];
      hi.z = aR[a * 4 + 3]; hi.w = aI[a * 4 + 3];
      float4 c0, c1;
      if (k == 0) {
        const float* pr = biasr + no * 4;
        const float* pi = biasi + no * 4;
        c0 = make_float4(pr[0], pi[0], pr[1], pi[1]);
        c1 = make_float4(pr[2], pi[2], pr[3], pi[3]);
      } else {
        c0 = *(const float4*)(po);
        c1 = *(const float4*)(po + 4);
      }
      lo.x += c0.x; lo.y += c0.y; lo.z += c0.z; lo.w += c0.w;
      hi.x += c1.x; hi.y += c1.y; hi.z += c1.z; hi.w += c1.w;
      *(float4*)(po) = lo;
      *(float4*)(po + 4) = hi;
    }
  }
}

// ---------------------------------------------------------------------------
extern "C" void kernel_launch(void* const* d_in, const int* in_sizes, int n_in,
                              void* d_out, int out_size, void* d_ws, size_t ws_size,
                              hipStream_t stream) {
  (void)in_sizes; (void)n_in;
  const float* xr = (const float*)d_in[0];
  const float* xi = (const float*)d_in[1];
  const float* gr = (const float*)d_in[2];
  const float* gi = (const float*)d_in[3];
  const float* wr = (const float*)d_in[4];
  const float* wi = (const float*)d_in[5];
  const float* biasr = (const float*)d_in[6];
  const float* biasi = (const float*)d_in[7];
  float* out = (float*)d_out;

  const size_t PPLANE = (size_t)Jn * 4096 * sizeof(f16);  // 67,108,864 (combined)
  const size_t GPLANE = (size_t)Nn * Nn * sizeof(f16);    // 8,388,608
  const size_t WPK = (size_t)Kn * TAUn * CIn * COn * 8;   // 147,456
  if (ws_size < 2 * PPLANE + 2 * GPLANE + WPK) return;

  char* ws = (char*)d_ws;
  f16* P0 = (f16*)(ws);
  f16* P1 = (f16*)(ws + PPLANE);
  f16* Gr = (f16*)(ws + 2 * PPLANE);
  f16* Gi = (f16*)(ws + 2 * PPLANE + GPLANE);
  uint2* wpk = (uint2*)(ws + 2 * PPLANE + 2 * GPLANE);

  const bool cplx = (out_size == 2 * Bn * Nn * Tn * COn);

  pack_gso<<<dim3(4096), dim3(256), 0, stream>>>(gr, gi, Gr, Gi);
  pack_x<<<dim3(32, 32, 4), dim3(256), 0, stream>>>(xr, xi, P0);
  pack_w<<<dim3(72), dim3(256), 0, stream>>>(wr, wi, wpk);

  #define CONTRACT(KK, Pp)                                                         \
    do {                                                                           \
      if (cplx)                                                                    \
        contract_k<true><<<dim3(32, 64, 4), dim3(256), 0, stream>>>(               \
            Pp, wpk, biasr, biasi, out, KK);                                       \
      else                                                                         \
        contract_k<false><<<dim3(32, 64, 4), dim3(256), 0, stream>>>(              \
            Pp, wpk, biasr, biasi, out, KK);                                       \
    } while (0)

  CONTRACT(0, P0);
  cheb_gemm<0><<<dim3(512), dim3(512), 131072, stream>>>(Gr, Gi, P0, P1);
  CONTRACT(1, P1);
  cheb_gemm<1><<<dim3(512), dim3(512), 131072, stream>>>(Gr, Gi, P1, P0);
  CONTRACT(2, P0);
  cheb_gemm<1><<<dim3(512), dim3(512), 131072, stream>>>(Gr, Gi, P0, P1);
  CONTRACT(3, P1);
  cheb_gemm<1><<<dim3(512), dim3(512), 131072, stream>>>(Gr, Gi, P1, P0);
  CONTRACT(4, P0);
  cheb_gemm<1><<<dim3(512), dim3(512), 131072, stream>>>(Gr, Gi, P0, P1);
  CONTRACT(5, P1);
  #undef CONTRACT
}